// Round 7
// baseline (191.630 us; speedup 1.0000x reference)
//
#include <hip/hip_runtime.h>

// Label attention: out = softmax(H @ W^T) @ W, fused, bf16 MFMA, no-max softmax.
// R6: barrier-minimal restructure. GEMM1 operand-swapped (S^T = W @ H^T) so each
// lane holds one token's P-slice in registers -> exp + pack + one shfl_xor(32)
// builds GEMM2 A-frags IN-REGISTER (no P LDS, no mid-iter barrier, no lgkm drain).
// GEMM2 accumulates partial-O over FULL d per wave (n-split across wc pair,
// o[8] = 128 acc regs); partials combined once per stream via retired W-buffer
// LDS. One s_barrier per iter -> waves drift, exp(VALU) overlaps MFMA cross-wave.
// R5 was lockstep-bound: MFMA 19.5%, VALU 18.7%, ~55% stall at 2 barriers/iter.

#define TM 128
#define DD 256
#define THREADS 512
#define TOK 32768

typedef __bf16 bf16t;
typedef bf16t v8bf __attribute__((ext_vector_type(8)));
typedef float v16f __attribute__((ext_vector_type(16)));

// LDS layout (byte offsets)
#define WT0   0        // Wt tile buf0: 32 frags * 1KB (A-frags for GEMM1)
#define WT1   32768    // Wt tile buf1
#define W20   65536    // W2 tile buf0: 32 frags * 1KB (B-frags for GEMM2)
#define W21   98304    // W2 tile buf1
#define L_OFF 131072   // row sums: 128 * 4B (W buffers double as O-exchange in epilogue)
#define LDS_BYTES 131584

// ws layout: frag-major bf16 images (1KB per wave-frag = 64 lanes * 16B)
#define IWT 0          // intent Wt: 8 tiles * 32KB
#define SWT 262144     // slot  Wt: 16 tiles * 32KB
#define IW2 786432     // intent W2: 8 tiles * 32KB
#define SW2 1048576    // slot  W2: 16 tiles * 32KB

__device__ __forceinline__ unsigned short f2bf(float x) {
    unsigned u = __builtin_bit_cast(unsigned, x);
    unsigned r = u + 0x7fffu + ((u >> 16) & 1u);
    return (unsigned short)(r >> 16);
}

// ---- prep: build frag-major bf16 W images in ws (unchanged) ----
// Wt frag (tile it, wc, kk): lane l holds W[it*64+wc*32+(l&31)][kk*16+(l>>5)*8+j]
// W2 frag (tile it, kb, db): lane l holds W[it*64+kb*16+(l>>5)*8+j][db*32+(l&31)]
__global__ __launch_bounds__(256) void prep_w_kernel(
    const float* __restrict__ w_int, const float* __restrict__ w_slot,
    char* __restrict__ wsb)
{
    int t = blockIdx.x * 256 + threadIdx.x;
    int w = t >> 6, lane = t & 63;
    int hi = lane >> 5, l5 = lane & 31;
    union { unsigned short u[8]; uint4 q; } pk;

    if (w < 768) {                       // Wt images (256 intent + 512 slot waves)
        int st   = (w >= 256);
        int widx = w - (st ? 256 : 0);
        int it = widx >> 5, fid = widx & 31;
        int wc = fid >> 4, kk = fid & 15;
        const float* W = st ? w_slot : w_int;
        int n  = it * 64 + wc * 32 + l5;
        int k0 = kk * 16 + hi * 8;
        #pragma unroll
        for (int j = 0; j < 8; ++j) pk.u[j] = f2bf(W[(size_t)n * DD + k0 + j]);
        char* dst = wsb + (st ? SWT : IWT) + (size_t)it * 32768 + fid * 1024 + lane * 16;
        *(uint4*)dst = pk.q;
    } else {                             // W2 images
        int w2 = w - 768;
        int st   = (w2 >= 256);
        int widx = w2 - (st ? 256 : 0);
        int it = widx >> 5, fid = widx & 31;
        int kb = fid >> 3, db = fid & 7;
        const float* W = st ? w_slot : w_int;
        int n0 = it * 64 + kb * 16 + hi * 8;
        int d  = db * 32 + l5;
        #pragma unroll
        for (int j = 0; j < 8; ++j) pk.u[j] = f2bf(W[(size_t)(n0 + j) * DD + d]);
        char* dst = wsb + (st ? SW2 : IW2) + (size_t)it * 32768 + fid * 1024 + lane * 16;
        *(uint4*)dst = pk.q;
    }
}

__global__ __launch_bounds__(THREADS)
__attribute__((amdgpu_waves_per_eu(2, 2)))
void label_attn_kernel(
    const float* __restrict__ in_intent,
    const float* __restrict__ in_slot,
    const char* __restrict__ wsb,
    float* __restrict__ out)
{
    extern __shared__ char lds[];

    const int tid  = threadIdx.x;
    const int lane = tid & 63;
    const int wid  = tid >> 6;
    const int wr   = wid >> 1;          // token group (32 rows each)
    const int wc   = wid & 1;           // n-half (both GEMMs; d is FULL per wave)
    const int hi   = lane >> 5;
    const int l5   = lane & 31;
    const int t0   = blockIdx.x * TM;

    float* lsf = (float*)(lds + L_OFF);

    for (int st = 0; st < 2; ++st) {
        __builtin_amdgcn_s_barrier();          // prev stream fully done
        if (tid < TM) lsf[tid] = 0.0f;

        const float* __restrict__ inp = st ? in_slot : in_intent;
        const char*  __restrict__ wtg = wsb + (st ? SWT : IWT);
        const char*  __restrict__ w2g = wsb + (st ? SW2 : IW2);
        const int niter = st ? 16 : 8;
        float* __restrict__ outp = out + (size_t)st * TOK * DD;

        // ---- issue DMA for tile 0 first (latency hides under h-load) ----
        #pragma unroll
        for (int c = 0; c < 4; ++c) {
            int chunk = wid * 4 + c;
            __builtin_amdgcn_global_load_lds(
                (const __attribute__((address_space(1))) unsigned*)(wtg + chunk * 1024 + lane * 16),
                (__attribute__((address_space(3))) unsigned*)(lds + WT0 + chunk * 1024),
                16, 0, 0);
        }
        __builtin_amdgcn_sched_barrier(0);
        #pragma unroll
        for (int c = 0; c < 4; ++c) {
            int chunk = wid * 4 + c;
            __builtin_amdgcn_global_load_lds(
                (const __attribute__((address_space(1))) unsigned*)(w2g + chunk * 1024 + lane * 16),
                (__attribute__((address_space(3))) unsigned*)(lds + W20 + chunk * 1024),
                16, 0, 0);
        }
        __builtin_amdgcn_sched_barrier(0);

        // ---- H -> registers (B-frags: token = lane&31, k = hi*8 + kk*16) ----
        v8bf h[16];
        {
            const float* hp = inp + (size_t)(t0 + wr * 32 + l5) * DD + hi * 8;
            #pragma unroll
            for (int kk = 0; kk < 16; ++kk) {
                float4 a = *(const float4*)(hp + kk * 16);
                float4 b = *(const float4*)(hp + kk * 16 + 4);
                union { unsigned short u[8]; v8bf v; } pk;
                pk.u[0] = f2bf(a.x); pk.u[1] = f2bf(a.y);
                pk.u[2] = f2bf(a.z); pk.u[3] = f2bf(a.w);
                pk.u[4] = f2bf(b.x); pk.u[5] = f2bf(b.y);
                pk.u[6] = f2bf(b.z); pk.u[7] = f2bf(b.w);
                h[kk] = pk.v;
            }
        }

        asm volatile("s_waitcnt vmcnt(0)" ::: "memory");   // tile 0 + h resident
        __builtin_amdgcn_sched_barrier(0);
        __builtin_amdgcn_s_barrier();

        v16f  o[8] = {};     // partial O: full 256 d, wave's n-half only
        float ls = 0.0f;     // lane-local partial denominator (token = lane&31)

        for (int it = 0; it < niter; ++it) {
            char* wt_buf = lds + ((it & 1) ? WT1 : WT0);
            char* w2_buf = lds + ((it & 1) ? W21 : W20);

            // issue next-tile DMA into alternate buffers
            if (it + 1 < niter) {
                const char* s1 = wtg + (size_t)(it + 1) * 32768;
                const char* s2 = w2g + (size_t)(it + 1) * 32768;
                char* d1 = lds + ((it & 1) ? WT0 : WT1);
                char* d2 = lds + ((it & 1) ? W20 : W21);
                #pragma unroll
                for (int c = 0; c < 4; ++c) {
                    int chunk = wid * 4 + c;
                    __builtin_amdgcn_global_load_lds(
                        (const __attribute__((address_space(1))) unsigned*)(s1 + chunk * 1024 + lane * 16),
                        (__attribute__((address_space(3))) unsigned*)(d1 + chunk * 1024),
                        16, 0, 0);
                }
                #pragma unroll
                for (int c = 0; c < 4; ++c) {
                    int chunk = wid * 4 + c;
                    __builtin_amdgcn_global_load_lds(
                        (const __attribute__((address_space(1))) unsigned*)(s2 + chunk * 1024 + lane * 16),
                        (__attribute__((address_space(3))) unsigned*)(d2 + chunk * 1024),
                        16, 0, 0);
                }
                __builtin_amdgcn_sched_barrier(0);
            }

            // ---- GEMM1 (swapped): S^T[32n x 32t] = W @ H^T ----
            // A = Wt frag (LDS, linear), B = h regs. Lane holds token t=lane&31,
            // n = (r&3)+8*(r>>2)+4*hi within the wave's 32-n slice.
            v16f cacc = {};
            #pragma unroll
            for (int kk = 0; kk < 16; ++kk) {
                v8bf a = *(const v8bf*)(wt_buf + (wc * 16 + kk) * 1024 + lane * 16);
                cacc = __builtin_amdgcn_mfma_f32_32x32x16_bf16(a, h[kk], cacc, 0, 0, 0);
            }

            // ---- exp + bf16 pack (pairs of consecutive n) + denom accum ----
            unsigned pkq[8];
            #pragma unroll
            for (int q = 0; q < 4; ++q) {
                unsigned short u0 = f2bf(__expf(cacc[4 * q + 0]));
                unsigned short u1 = f2bf(__expf(cacc[4 * q + 1]));
                unsigned short u2 = f2bf(__expf(cacc[4 * q + 2]));
                unsigned short u3 = f2bf(__expf(cacc[4 * q + 3]));
                ls += __builtin_bit_cast(float, ((unsigned)u0) << 16);
                ls += __builtin_bit_cast(float, ((unsigned)u1) << 16);
                ls += __builtin_bit_cast(float, ((unsigned)u2) << 16);
                ls += __builtin_bit_cast(float, ((unsigned)u3) << 16);
                pkq[2 * q]     = (unsigned)u0 | ((unsigned)u1 << 16);
                pkq[2 * q + 1] = (unsigned)u2 | ((unsigned)u3 << 16);
            }
            // cross-half exchange: partner lane (same token, other hi)
            unsigned oth[8];
            #pragma unroll
            for (int i = 0; i < 8; ++i)
                oth[i] = (unsigned)__shfl_xor((int)pkq[i], 32);

            // ---- GEMM2: O[32t x 256d] += P_half @ W2 (A regs, B LDS linear) ----
            #pragma unroll
            for (int kb = 0; kb < 2; ++kb) {
                uint4 sel;
                sel.x = hi ? oth[4 * kb + 2] : pkq[4 * kb + 0];
                sel.y = hi ? oth[4 * kb + 3] : pkq[4 * kb + 1];
                sel.z = hi ? pkq[4 * kb + 2] : oth[4 * kb + 0];
                sel.w = hi ? pkq[4 * kb + 3] : oth[4 * kb + 1];
                v8bf pa = __builtin_bit_cast(v8bf, sel);
                #pragma unroll
                for (int db = 0; db < 8; ++db) {
                    v8bf wb = *(const v8bf*)(w2_buf + ((wc * 2 + kb) * 8 + db) * 1024 + lane * 16);
                    o[db] = __builtin_amdgcn_mfma_f32_32x32x16_bf16(pa, wb, o[db], 0, 0, 0);
                }
            }

            asm volatile("s_waitcnt vmcnt(0)" ::: "memory");  // own next-tile DMA landed
            __builtin_amdgcn_sched_barrier(0);
            __builtin_amdgcn_s_barrier();                     // swap buffers
        }

        // ---- epilogue ----
        // denominator: own half + partner half, then cross-wc via LDS atomic
        float s = ls + __shfl_xor(ls, 32);
        if (lane < 32) atomicAdd(&lsf[wr * 32 + lane], s);

        // partial-O exchange: wc=0 writes its partials into retired W buffers
        if (wc == 0) {
            float* reg = (float*)(lds + wr * 32768);
            #pragma unroll
            for (int db = 0; db < 8; ++db)
                #pragma unroll
                for (int r = 0; r < 16; ++r)
                    reg[(db * 16 + r) * 64 + lane] = o[db][r];
        }
        __syncthreads();

        if (wc == 1) {
            const float* reg = (const float*)(lds + wr * 32768);
            #pragma unroll
            for (int r = 0; r < 16; ++r) {
                int tl = (r & 3) + 8 * (r >> 2) + 4 * hi;
                float inv = 1.0f / lsf[wr * 32 + tl];
                size_t row = (size_t)(t0 + wr * 32 + tl);
                #pragma unroll
                for (int db = 0; db < 8; ++db) {
                    float tot = o[db][r] + reg[(db * 16 + r) * 64 + lane];
                    outp[row * DD + db * 32 + l5] = tot * inv;
                }
            }
        }
    }
}

extern "C" void kernel_launch(void* const* d_in, const int* in_sizes, int n_in,
                              void* d_out, int out_size, void* d_ws, size_t ws_size,
                              hipStream_t stream) {
    const float* in_intent = (const float*)d_in[0];
    const float* in_slot   = (const float*)d_in[1];
    // d_in[2] = mask (unused)
    const float* w_intent  = (const float*)d_in[3];
    const float* w_slot    = (const float*)d_in[4];
    float* out = (float*)d_out;
    char* wsb = (char*)d_ws;

    (void)hipFuncSetAttribute((const void*)label_attn_kernel,
                              hipFuncAttributeMaxDynamicSharedMemorySize, LDS_BYTES);

    // prep: 1536 frag-waves -> 384 blocks of 256
    prep_w_kernel<<<384, 256, 0, stream>>>(w_intent, w_slot, wsb);

    label_attn_kernel<<<dim3(TOK / TM, 1, 1), dim3(THREADS, 1, 1), LDS_BYTES, stream>>>(
        in_intent, in_slot, wsb, out);
}